// Round 5
// baseline (1616.865 us; speedup 1.0000x reference)
//
#include <hip/hip_runtime.h>

// AssocScan single-pass: out[:, t] = gates[:, t] * out[:, t-1] + inputs[:, t]
// (B, N, D) = (4, 4096, 1024) fp32. Decoupled-lookback chunked scan, ONE kernel.
//
//   grid = B*kC = 1024 blocks, 256 threads (one float4 channel-group each).
//   Block (b, c): read tile (kT=16 rows) once; local (A = prod g, KV);
//   publish locals (agent-scope atomic u64, LLC-coherent cross-XCD); batched
//   lookback over predecessors (window kW flags); publish inclusive h;
//   recompute outputs from carry (tile re-read is LLC/L2-hot); store.
//
//   flags: 0 = not ready, 1 = local published, 2 = inclusive published.
//   ws is poisoned 0xAA before every launch -> ticket+flags zeroed via
//   hipMemsetAsync (graph-capturable). Ticket makes chunk assignment monotonic
//   in dispatch order -> forward progress guaranteed even without co-residency.
//
//   R4: kW=6 (was 8) to keep lookback Lv[] under the 128-VGPR cap of
//   __launch_bounds__(256,4) — a spill there would sit on the critical path.

namespace {
constexpr int kB = 4;
constexpr int kN = 4096;
constexpr int kD4 = 256;                 // float4 groups per row
constexpr int kC = 256;                  // chunks per batch chain
constexpr int kT = kN / kC;              // 16 rows per chunk
constexpr int kBlocks = kB * kC;         // 1024
constexpr int kW = 6;                    // lookback window (flags per poll)
constexpr size_t kCtrlBytes = 8192;      // [0]=ticket, [64..]=flags (kBlocks u32)
}  // namespace

using u64 = unsigned long long;

__device__ __forceinline__ u64 pack2(float hi, float lo) {
  union { float f; unsigned u; } a, b;
  a.f = hi; b.f = lo;
  return ((u64)a.u << 32) | (u64)b.u;
}
__device__ __forceinline__ void unpack2(u64 v, float& hi, float& lo) {
  union { unsigned u; float f; } a, b;
  a.u = (unsigned)(v >> 32); b.u = (unsigned)v;
  hi = a.f; lo = b.f;
}

__global__ __launch_bounds__(256, 4) void assoc_scan_onepass(
    const float4* __restrict__ g, const float4* __restrict__ x,
    float4* __restrict__ out, unsigned* __restrict__ ctrl) {
  unsigned* ticket = ctrl;                       // [0]
  unsigned* flags  = ctrl + 16;                  // kBlocks u32
  u64* agg  = (u64*)((char*)ctrl + kCtrlBytes);              // [kBlocks][kD4][4] (A,KV)
  u64* incl = agg + (size_t)kBlocks * kD4 * 4;               // [kBlocks][kD4][2] (h)

  __shared__ unsigned s_tix;
  if (threadIdx.x == 0) s_tix = atomicAdd(ticket, 1u);
  __syncthreads();
  const int b = (int)(s_tix & 3u);               // batch fastest -> per-chain monotone
  const int c = (int)(s_tix >> 2);
  const int d4 = threadIdx.x;
  const int fbase = b * kC;

  // ---- pass 1: local aggregate over the tile ----
  const size_t base = ((size_t)b * kN + (size_t)c * kT) * kD4 + d4;
  const float4* gp = g + base;
  const float4* xp = x + base;
  float4 A  = make_float4(1.f, 1.f, 1.f, 1.f);
  float4 KV = make_float4(0.f, 0.f, 0.f, 0.f);
#pragma unroll
  for (int i = 0; i < kT; ++i) {
    const float4 gv = gp[(size_t)i * kD4];
    const float4 xv = xp[(size_t)i * kD4];
    KV.x = fmaf(gv.x, KV.x, xv.x);
    KV.y = fmaf(gv.y, KV.y, xv.y);
    KV.z = fmaf(gv.z, KV.z, xv.z);
    KV.w = fmaf(gv.w, KV.w, xv.w);
    A.x *= gv.x; A.y *= gv.y; A.z *= gv.z; A.w *= gv.w;
  }

  // ---- publish local (chunk 0 publishes inclusive directly) ----
  if (c == 0) {
    u64* ip = incl + ((size_t)(fbase) * kD4 + d4) * 2;
    __hip_atomic_store(ip + 0, pack2(KV.x, KV.y), __ATOMIC_RELAXED, __HIP_MEMORY_SCOPE_AGENT);
    __hip_atomic_store(ip + 1, pack2(KV.z, KV.w), __ATOMIC_RELAXED, __HIP_MEMORY_SCOPE_AGENT);
  } else {
    u64* ap = agg + ((size_t)(fbase + c) * kD4 + d4) * 4;
    __hip_atomic_store(ap + 0, pack2(A.x, KV.x), __ATOMIC_RELAXED, __HIP_MEMORY_SCOPE_AGENT);
    __hip_atomic_store(ap + 1, pack2(A.y, KV.y), __ATOMIC_RELAXED, __HIP_MEMORY_SCOPE_AGENT);
    __hip_atomic_store(ap + 2, pack2(A.z, KV.z), __ATOMIC_RELAXED, __HIP_MEMORY_SCOPE_AGENT);
    __hip_atomic_store(ap + 3, pack2(A.w, KV.w), __ATOMIC_RELAXED, __HIP_MEMORY_SCOPE_AGENT);
  }
  __threadfence();
  __syncthreads();
  if (threadIdx.x == 0) {
    __hip_atomic_store(&flags[fbase + c], (c == 0) ? 2u : 1u,
                       __ATOMIC_RELEASE, __HIP_MEMORY_SCOPE_AGENT);
  }

  // ---- lookback: carry = h entering this chunk ----
  float4 carry = make_float4(0.f, 0.f, 0.f, 0.f);
  if (c > 0) {
    float4 accA = make_float4(1.f, 1.f, 1.f, 1.f);
    float4 accK = make_float4(0.f, 0.f, 0.f, 0.f);
    int p = c - 1;
    bool done = false;
    while (!done) {
      unsigned fl[kW];
#pragma unroll
      for (int j = 0; j < kW; ++j) {
        const int q = p - j;
        fl[j] = (q >= 0)
            ? __hip_atomic_load(&flags[fbase + q], __ATOMIC_ACQUIRE, __HIP_MEMORY_SCOPE_AGENT)
            : 2u;  // sentinel: "inclusive" with h = 0
      }
      if (fl[0] == 0u) { __builtin_amdgcn_s_sleep(1); continue; }
      // steps = locals to consume (j=0..steps-1); term = j of terminal (>=2) or -1
      int steps = kW, term = -1;
#pragma unroll
      for (int j = kW - 1; j >= 0; --j) {
        if (fl[j] == 0u)      { steps = j; term = -1; }
        else if (fl[j] >= 2u) { steps = j; term = j; }
      }
      // load locals (static unroll, exec-masked)
      u64 Lv[kW][4];
#pragma unroll
      for (int j = 0; j < kW; ++j) {
        if (j < steps) {
          const u64* ap = agg + ((size_t)(fbase + (p - j)) * kD4 + d4) * 4;
          Lv[j][0] = __hip_atomic_load(ap + 0, __ATOMIC_RELAXED, __HIP_MEMORY_SCOPE_AGENT);
          Lv[j][1] = __hip_atomic_load(ap + 1, __ATOMIC_RELAXED, __HIP_MEMORY_SCOPE_AGENT);
          Lv[j][2] = __hip_atomic_load(ap + 2, __ATOMIC_RELAXED, __HIP_MEMORY_SCOPE_AGENT);
          Lv[j][3] = __hip_atomic_load(ap + 3, __ATOMIC_RELAXED, __HIP_MEMORY_SCOPE_AGENT);
        }
      }
      float4 hq = make_float4(0.f, 0.f, 0.f, 0.f);
      if (term >= 0) {
        const int q = p - term;
        if (q >= 0) {
          const u64* ip = incl + ((size_t)(fbase + q) * kD4 + d4) * 2;
          const u64 v0 = __hip_atomic_load(ip + 0, __ATOMIC_RELAXED, __HIP_MEMORY_SCOPE_AGENT);
          const u64 v1 = __hip_atomic_load(ip + 1, __ATOMIC_RELAXED, __HIP_MEMORY_SCOPE_AGENT);
          unpack2(v0, hq.x, hq.y);
          unpack2(v1, hq.z, hq.w);
        }
      }
      // combine locals in descending-p order: acc' = acc o chunk_q
#pragma unroll
      for (int j = 0; j < kW; ++j) {
        if (j < steps) {
          float4 a, k;
          unpack2(Lv[j][0], a.x, k.x);
          unpack2(Lv[j][1], a.y, k.y);
          unpack2(Lv[j][2], a.z, k.z);
          unpack2(Lv[j][3], a.w, k.w);
          accK.x = fmaf(accA.x, k.x, accK.x);
          accK.y = fmaf(accA.y, k.y, accK.y);
          accK.z = fmaf(accA.z, k.z, accK.z);
          accK.w = fmaf(accA.w, k.w, accK.w);
          accA.x *= a.x; accA.y *= a.y; accA.z *= a.z; accA.w *= a.w;
        }
      }
      if (term >= 0) {
        carry.x = fmaf(accA.x, hq.x, accK.x);
        carry.y = fmaf(accA.y, hq.y, accK.y);
        carry.z = fmaf(accA.z, hq.z, accK.z);
        carry.w = fmaf(accA.w, hq.w, accK.w);
        done = true;
      } else {
        p -= steps;
      }
    }

    // ---- publish inclusive h for this chunk ----
    float4 hend;
    hend.x = fmaf(A.x, carry.x, KV.x);
    hend.y = fmaf(A.y, carry.y, KV.y);
    hend.z = fmaf(A.z, carry.z, KV.z);
    hend.w = fmaf(A.w, carry.w, KV.w);
    u64* ip = incl + ((size_t)(fbase + c) * kD4 + d4) * 2;
    __hip_atomic_store(ip + 0, pack2(hend.x, hend.y), __ATOMIC_RELAXED, __HIP_MEMORY_SCOPE_AGENT);
    __hip_atomic_store(ip + 1, pack2(hend.z, hend.w), __ATOMIC_RELAXED, __HIP_MEMORY_SCOPE_AGENT);
    __threadfence();
    __syncthreads();
    if (threadIdx.x == 0) {
      __hip_atomic_store(&flags[fbase + c], 2u, __ATOMIC_RELEASE, __HIP_MEMORY_SCOPE_AGENT);
    }
  }

  // ---- pass 2: recompute recurrence from carry, store outputs ----
  float4 h = carry;
  float4* op = out + base;
#pragma unroll
  for (int i = 0; i < kT; ++i) {
    const float4 gv = gp[(size_t)i * kD4];
    const float4 xv = xp[(size_t)i * kD4];
    h.x = fmaf(gv.x, h.x, xv.x);
    h.y = fmaf(gv.y, h.y, xv.y);
    h.z = fmaf(gv.z, h.z, xv.z);
    h.w = fmaf(gv.w, h.w, xv.w);
    op[(size_t)i * kD4] = h;
  }
}

extern "C" void kernel_launch(void* const* d_in, const int* in_sizes, int n_in,
                              void* d_out, int out_size, void* d_ws, size_t ws_size,
                              hipStream_t stream) {
  const float4* g = (const float4*)d_in[0];   // gates  (B,N,D) fp32
  const float4* x = (const float4*)d_in[1];   // inputs (B,N,D) fp32
  float4* out = (float4*)d_out;

  // zero ticket + flags (ws is 0xAA-poisoned before every launch)
  hipMemsetAsync(d_ws, 0, kCtrlBytes, stream);
  assoc_scan_onepass<<<kBlocks, 256, 0, stream>>>(g, x, out, (unsigned*)d_ws);
}